// Round 2
// baseline (1761.195 us; speedup 1.0000x reference)
//
#include <hip/hip_runtime.h>
#include <hip/hip_bf16.h>

static constexpr int NN = 100000;
static constexpr int NE = 3200000;
static constexpr int NG = 512;

// ---- degree: deg[i] = in-degree(dst) ; then dis = rsqrt(deg+1) -------------
__global__ __launch_bounds__(256) void k_count(const int* __restrict__ dst,
                                               float* __restrict__ deg, int e) {
    int i = blockIdx.x * 256 + threadIdx.x;
    if (i < e) atomicAdd(&deg[dst[i]], 1.0f);
}

__global__ __launch_bounds__(256) void k_dis(float* deg_dis, int n) {
    int i = blockIdx.x * 256 + threadIdx.x;
    if (i < n) deg_dis[i] = rsqrtf(deg_dis[i] + 1.0f);
}

// ---- GEMM: h = X@W. SELFLOOP: writes H=h and A = h*dis^2 + b (layer-1 path).
//      else: A = h + b (aggregate-first path, layers 2/3). ------------------
template <int IN, int OUTD, int ROWS, int CPT, bool SELFLOOP>
__global__ __launch_bounds__(ROWS*(OUTD/CPT)) void k_gemm(
        const float* __restrict__ X, const float* __restrict__ W,
        const float* __restrict__ b, const float* __restrict__ dis,
        float* __restrict__ H, float* __restrict__ A, int n) {
    constexpr int CT = OUTD / CPT;   // column-threads per row
    constexpr int NT = ROWS * CT;    // block size
    __shared__ float sW[IN * OUTD];
    __shared__ float sX[ROWS * IN];
    const int tid = threadIdx.x;
    for (int i = tid; i < IN * OUTD; i += NT) sW[i] = W[i];
    const int row0 = blockIdx.x * ROWS;
    for (int i = tid; i < ROWS * IN; i += NT) {
        int r = row0 + i / IN;
        sX[i] = (r < n) ? X[(size_t)r * IN + i % IN] : 0.f;
    }
    __syncthreads();
    const int lr = tid / CT;
    const int c0 = tid % CT;
    const int gr = row0 + lr;
    float acc[CPT];
#pragma unroll
    for (int c = 0; c < CPT; c++) acc[c] = 0.f;
#pragma unroll 8
    for (int k = 0; k < IN; k++) {
        float xv = sX[lr * IN + k];
#pragma unroll
        for (int c = 0; c < CPT; c++)
            acc[c] = fmaf(xv, sW[k * OUTD + c0 + c * CT], acc[c]);
    }
    if (gr < n) {
        if (SELFLOOP) {
            float d = dis[gr];
            float d2 = d * d;
#pragma unroll
            for (int c = 0; c < CPT; c++) {
                int col = c0 + c * CT;
                H[(size_t)gr * OUTD + col] = acc[c];
                A[(size_t)gr * OUTD + col] = fmaf(acc[c], d2, b[col]);
            }
        } else {
#pragma unroll
            for (int c = 0; c < CPT; c++) {
                int col = c0 + c * CT;
                A[(size_t)gr * OUTD + col] = acc[c] + b[col];
            }
        }
    }
}

// ---- edge scatter: A[dst] += (relu?)(H[src]) * dis[src]*dis[dst] ----------
template <int OUTD, bool RELU>
__global__ __launch_bounds__(256) void k_scatter(
        const int* __restrict__ src, const int* __restrict__ dst,
        const float* __restrict__ dis, const float* __restrict__ H,
        float* __restrict__ A, int e) {
    long long t = (long long)blockIdx.x * 256 + threadIdx.x;
    int eid = (int)(t / OUTD);
    int j   = (int)(t % OUTD);
    if (eid < e) {
        int s = src[eid], d = dst[eid];
        float norm = dis[s] * dis[d];
        float v = H[(size_t)s * OUTD + j];
        if (RELU) v = fmaxf(v, 0.f);
        atomicAdd(&A[(size_t)d * OUTD + j], v * norm);
    }
}

// ---- y = relu(A) * dis^2  (self-loop init for aggregate-first layers) -----
template <int D>
__global__ __launch_bounds__(256) void k_selfinit(
        const float* __restrict__ A, const float* __restrict__ dis,
        float* __restrict__ y, int n) {
    long long t = (long long)blockIdx.x * 256 + threadIdx.x;
    if (t < (long long)n * D) {
        int node = (int)(t / D);
        float d = dis[node];
        y[t] = fmaxf(A[t], 0.f) * d * d;
    }
}

// ---- global mean pool: sums[g] += relu(A3[node]), cnt[g] += 1 -------------
__global__ __launch_bounds__(256) void k_pool(
        const float* __restrict__ A3, const int* __restrict__ batch,
        float* __restrict__ sums, float* __restrict__ cnt, int n) {
    long long t = (long long)blockIdx.x * 256 + threadIdx.x;
    if (t < (long long)n * 64) {
        int node = (int)(t >> 6);
        int j    = (int)(t & 63);
        int g = batch[node];
        atomicAdd(&sums[g * 64 + j], fmaxf(A3[t], 0.f));
        if (j == 0) atomicAdd(&cnt[g], 1.0f);
    }
}

// ---- head: mean -> fc1+relu -> fc2 -> softmax, one block per graph --------
__global__ __launch_bounds__(64) void k_head(
        const float* __restrict__ sums, const float* __restrict__ cnt,
        const float* __restrict__ f1w, const float* __restrict__ f1b,
        const float* __restrict__ f2w, const float* __restrict__ f2b,
        float* __restrict__ out) {
    int g = blockIdx.x;
    int t = threadIdx.x;
    __shared__ float p[64], z[32], lg[16];
    float c = fmaxf(cnt[g], 1.0f);
    p[t] = sums[g * 64 + t] / c;
    __syncthreads();
    if (t < 32) {
        float acc = f1b[t];
        for (int j = 0; j < 64; j++)
            acc = fmaf(p[j], f1w[j * 32 + t], acc);
        z[t] = fmaxf(acc, 0.f);
    }
    __syncthreads();
    if (t < 16) {
        float acc = f2b[t];
        for (int k = 0; k < 32; k++)
            acc = fmaf(z[k], f2w[k * 16 + t], acc);
        lg[t] = acc;
    }
    __syncthreads();
    if (t < 16) {
        float m = lg[0];
        for (int i = 1; i < 16; i++) m = fmaxf(m, lg[i]);
        float s = 0.f;
        for (int i = 0; i < 16; i++) s += expf(lg[i] - m);
        out[g * 16 + t] = expf(lg[t] - m) / s;
    }
}

extern "C" void kernel_launch(void* const* d_in, const int* in_sizes, int n_in,
                              void* d_out, int out_size, void* d_ws, size_t ws_size,
                              hipStream_t stream) {
    (void)in_sizes; (void)n_in; (void)out_size; (void)ws_size;
    const float* x     = (const float*)d_in[0];
    const int*   ei    = (const int*)d_in[1];
    const int*   batch = (const int*)d_in[2];
    const float* W1 = (const float*)d_in[3];  const float* b1 = (const float*)d_in[4];
    const float* W2 = (const float*)d_in[5];  const float* b2 = (const float*)d_in[6];
    const float* W3 = (const float*)d_in[7];  const float* b3 = (const float*)d_in[8];
    const float* f1w = (const float*)d_in[9]; const float* f1b = (const float*)d_in[10];
    const float* f2w = (const float*)d_in[11];const float* f2b = (const float*)d_in[12];
    float* out = (float*)d_out;

    const int* src = ei;
    const int* dst = ei + NE;

    // Workspace layout with lifetime-based aliasing (~52 MB):
    //   P (NN*64): H1@[0,32N) [gemm1..scatter1]; y2@[0,32N) [selfinit2..gemm2];
    //              A1@[32N,64N) [gemm1..scatter2]; y3@[0,48N) [selfinit3..gemm3]
    //   Q (NN*64): A2@[0,48N) [gemm2..scatter3]; A3@[0,64N) [gemm3..pool]
    float* ws  = (float*)d_ws;
    size_t o = 0;
    float* dis = ws + o; o += NN;
    float* P   = ws + o; o += (size_t)NN * 64;
    float* Q   = ws + o; o += (size_t)NN * 64;
    float* sums= ws + o; o += (size_t)NG * 64;
    float* cnt = ws + o; o += NG;

    float* H1 = P;
    float* A1 = P + (size_t)NN * 32;
    float* y2 = P;
    float* y3 = P;
    float* A2 = Q;
    float* A3 = Q;

    hipMemsetAsync(dis, 0, NN * sizeof(float), stream);
    hipMemsetAsync(sums, 0, (NG * 64 + NG) * sizeof(float), stream);

    k_count<<<(NE + 255) / 256, 256, 0, stream>>>(dst, dis, NE);
    k_dis<<<(NN + 255) / 256, 256, 0, stream>>>(dis, NN);

    // Layer 1 (IN=128 > OUT=32): transform-first, scatter in 32-dim
    k_gemm<128, 32, 8, 1, true><<<(NN + 7) / 8, 256, 0, stream>>>(
        x, W1, b1, dis, H1, A1, NN);
    k_scatter<32, false><<<(int)(((long long)NE * 32 + 255) / 256), 256, 0, stream>>>(
        src, dst, dis, H1, A1, NE);

    // Layer 2 (IN=32 < OUT=48): aggregate-first, scatter relu(A1) in 32-dim
    k_selfinit<32><<<(int)(((long long)NN * 32 + 255) / 256), 256, 0, stream>>>(
        A1, dis, y2, NN);
    k_scatter<32, true><<<(int)(((long long)NE * 32 + 255) / 256), 256, 0, stream>>>(
        src, dst, dis, A1, y2, NE);
    k_gemm<32, 48, 16, 3, false><<<(NN + 15) / 16, 256, 0, stream>>>(
        y2, W2, b2, dis, nullptr, A2, NN);

    // Layer 3 (IN=48 < OUT=64): aggregate-first, scatter relu(A2) in 48-dim
    k_selfinit<48><<<(int)(((long long)NN * 48 + 255) / 256), 256, 0, stream>>>(
        A2, dis, y3, NN);
    k_scatter<48, true><<<(int)(((long long)NE * 48 + 255) / 256), 256, 0, stream>>>(
        src, dst, dis, A2, y3, NE);
    k_gemm<48, 64, 8, 2, false><<<(NN + 7) / 8, 256, 0, stream>>>(
        y3, W3, b3, dis, nullptr, A3, NN);

    // Pool + head
    k_pool<<<(int)(((long long)NN * 64 + 255) / 256), 256, 0, stream>>>(
        A3, batch, sums, cnt, NN);
    k_head<<<NG, 64, 0, stream>>>(sums, cnt, f1w, f1b, f2w, f2b, out);
}

// Round 3
// 977.850 us; speedup vs baseline: 1.8011x; 1.8011x over previous
//
#include <hip/hip_runtime.h>
#include <hip/hip_bf16.h>

static constexpr int NN = 100000;
static constexpr int NE = 3200000;
static constexpr int NG = 512;

// ---- degree (int) ----------------------------------------------------------
__global__ __launch_bounds__(256) void k_degree(const int* __restrict__ dst,
                                                int* __restrict__ degi, int e) {
    int i = blockIdx.x * 256 + threadIdx.x;
    if (i < e) atomicAdd(&degi[dst[i]], 1);
}

__global__ __launch_bounds__(256) void k_dis(const int* __restrict__ degi,
                                             float* __restrict__ dis, int n) {
    int i = blockIdx.x * 256 + threadIdx.x;
    if (i < n) dis[i] = rsqrtf((float)degi[i] + 1.0f);
}

// ---- exclusive scan of degi -> offs (3-kernel, 1024 elems/block) -----------
__global__ __launch_bounds__(256) void k_scan1(const int* __restrict__ degi,
                                               int* __restrict__ offs,
                                               int* __restrict__ bsum, int n) {
    __shared__ int s[256];
    const int tid = threadIdx.x;
    const int base = blockIdx.x * 1024 + tid * 4;
    int v[4], t = 0;
#pragma unroll
    for (int c = 0; c < 4; c++) {
        int idx = base + c;
        v[c] = (idx < n) ? degi[idx] : 0;
        t += v[c];
    }
    s[tid] = t;
    __syncthreads();
    for (int off = 1; off < 256; off <<= 1) {
        int x = (tid >= off) ? s[tid - off] : 0;
        __syncthreads();
        s[tid] += x;
        __syncthreads();
    }
    if (tid == 255) bsum[blockIdx.x] = s[255];
    int run = s[tid] - t;  // exclusive prefix of this thread
#pragma unroll
    for (int c = 0; c < 4; c++) {
        int idx = base + c;
        if (idx < n) offs[idx] = run;
        run += v[c];
    }
}

__global__ __launch_bounds__(128) void k_scan2(const int* __restrict__ bsum,
                                               int* __restrict__ bscan, int nb) {
    __shared__ int s[128];
    const int tid = threadIdx.x;
    int v = (tid < nb) ? bsum[tid] : 0;
    s[tid] = v;
    __syncthreads();
    for (int off = 1; off < 128; off <<= 1) {
        int x = (tid >= off) ? s[tid - off] : 0;
        __syncthreads();
        s[tid] += x;
        __syncthreads();
    }
    bscan[tid] = s[tid] - v;  // exclusive
}

__global__ __launch_bounds__(256) void k_scan3(int* __restrict__ offs,
                                               int* __restrict__ cursor,
                                               const int* __restrict__ bscan, int n) {
    int i = blockIdx.x * 256 + threadIdx.x;
    if (i < n) {
        int o = offs[i] + bscan[i >> 10];
        offs[i] = o;
        cursor[i] = o;
    }
}

// ---- CSR fill: csr[cursor[dst]++] = src ------------------------------------
__global__ __launch_bounds__(256) void k_fill(const int* __restrict__ src,
                                              const int* __restrict__ dst,
                                              int* __restrict__ cursor,
                                              int* __restrict__ csr, int e) {
    int i = blockIdx.x * 256 + threadIdx.x;
    if (i < e) {
        int p = atomicAdd(&cursor[dst[i]], 1);
        csr[p] = src[i];
    }
}

// ---- gemm1: H1' = (x @ W1) * dis[row]  (128 -> 32) -------------------------
__global__ __launch_bounds__(256) void k_gemm1(const float* __restrict__ X,
                                               const float* __restrict__ W,
                                               const float* __restrict__ dis,
                                               float* __restrict__ H, int n) {
    constexpr int IN = 128, OUTD = 32, ROWS = 8;
    __shared__ float sW[IN * OUTD];
    __shared__ float sX[ROWS * IN];
    const int tid = threadIdx.x;
    for (int i = tid; i < IN * OUTD; i += 256) sW[i] = W[i];
    const int row0 = blockIdx.x * ROWS;
    for (int i = tid; i < ROWS * IN; i += 256) {
        int r = row0 + i / IN;
        sX[i] = (r < n) ? X[(size_t)r * IN + i % IN] : 0.f;
    }
    __syncthreads();
    const int lr = tid / OUTD;
    const int col = tid % OUTD;
    const int gr = row0 + lr;
    float acc = 0.f;
#pragma unroll 8
    for (int k = 0; k < IN; k++)
        acc = fmaf(sX[lr * IN + k], sW[k * OUTD + col], acc);
    if (gr < n) H[(size_t)gr * OUTD + col] = acc * dis[gr];
}

// ---- pull (layer1): out = f(dis[d]*(H'[d] + sum H'[src]) + b) --------------
// PRESCALE: out = relu(raw)*dis[d]  (produces next layer's prescaled operand)
template <int AGGD, int TPN, bool PRESCALE>
__global__ __launch_bounds__(256) void k_pull(
        const float* __restrict__ Hp, const int* __restrict__ offs,
        const int* __restrict__ degi, const int* __restrict__ csr,
        const float* __restrict__ dis, const float* __restrict__ b,
        float* __restrict__ A, int n) {
    constexpr int CPT = AGGD / TPN;
    constexpr int NPB = 256 / TPN;
    const int group = threadIdx.x / TPN, j0 = threadIdx.x % TPN;
    const int d = blockIdx.x * NPB + group;
    if (d >= n) return;
    const size_t selfbase = (size_t)d * AGGD + j0;
    float acc[CPT];
#pragma unroll
    for (int c = 0; c < CPT; c++) acc[c] = Hp[selfbase + c * TPN];
    int e = offs[d];
    const int end = e + degi[d];
    for (; e + 3 < end; e += 4) {
        int s0 = csr[e], s1 = csr[e + 1], s2 = csr[e + 2], s3 = csr[e + 3];
        size_t b0 = (size_t)s0 * AGGD + j0, b1 = (size_t)s1 * AGGD + j0;
        size_t b2 = (size_t)s2 * AGGD + j0, b3 = (size_t)s3 * AGGD + j0;
#pragma unroll
        for (int c = 0; c < CPT; c++)
            acc[c] += (Hp[b0 + c * TPN] + Hp[b1 + c * TPN]) +
                      (Hp[b2 + c * TPN] + Hp[b3 + c * TPN]);
    }
    for (; e < end; e++) {
        size_t bb = (size_t)csr[e] * AGGD + j0;
#pragma unroll
        for (int c = 0; c < CPT; c++) acc[c] += Hp[bb + c * TPN];
    }
    const float dd = dis[d];
#pragma unroll
    for (int c = 0; c < CPT; c++) {
        float raw = fmaf(acc[c], dd, b[j0 + c * TPN]);
        A[selfbase + c * TPN] = PRESCALE ? fmaxf(raw, 0.f) * dd : raw;
    }
}

// ---- fused pull + gemm (layers 2,3): y = dis*(self+sum); A = y@W + b -------
// PRESCALE: write relu(A)*dis instead of A (produces next prescaled operand)
template <int AGGD, int OUTD, int TPN, bool PRESCALE>
__global__ __launch_bounds__(256) void k_pull_mm(
        const float* __restrict__ Hp, const int* __restrict__ offs,
        const int* __restrict__ degi, const int* __restrict__ csr,
        const float* __restrict__ dis, const float* __restrict__ W,
        const float* __restrict__ b, float* __restrict__ A, int n) {
    constexpr int CPT = AGGD / TPN;
    constexpr int NPB = 256 / TPN;
    constexpr int OPT = (NPB * OUTD) / 256;
    __shared__ float sW[AGGD * OUTD];
    __shared__ float rows[NPB][AGGD];
    for (int i = threadIdx.x; i < AGGD * OUTD; i += 256) sW[i] = W[i];
    const int group = threadIdx.x / TPN, j0 = threadIdx.x % TPN;
    const int d = blockIdx.x * NPB + group;
    if (d < n) {
        const size_t selfbase = (size_t)d * AGGD + j0;
        float acc[CPT];
#pragma unroll
        for (int c = 0; c < CPT; c++) acc[c] = Hp[selfbase + c * TPN];
        int e = offs[d];
        const int end = e + degi[d];
        for (; e + 3 < end; e += 4) {
            int s0 = csr[e], s1 = csr[e + 1], s2 = csr[e + 2], s3 = csr[e + 3];
            size_t b0 = (size_t)s0 * AGGD + j0, b1 = (size_t)s1 * AGGD + j0;
            size_t b2 = (size_t)s2 * AGGD + j0, b3 = (size_t)s3 * AGGD + j0;
#pragma unroll
            for (int c = 0; c < CPT; c++)
                acc[c] += (Hp[b0 + c * TPN] + Hp[b1 + c * TPN]) +
                          (Hp[b2 + c * TPN] + Hp[b3 + c * TPN]);
        }
        for (; e < end; e++) {
            size_t bb = (size_t)csr[e] * AGGD + j0;
#pragma unroll
            for (int c = 0; c < CPT; c++) acc[c] += Hp[bb + c * TPN];
        }
        const float dd = dis[d];
#pragma unroll
        for (int c = 0; c < CPT; c++) rows[group][j0 + c * TPN] = acc[c] * dd;
    }
    __syncthreads();
    const int row0 = blockIdx.x * NPB;
#pragma unroll
    for (int o = 0; o < OPT; o++) {
        int idx = o * 256 + threadIdx.x;
        int nl = idx / OUTD, col = idx % OUTD;
        int gr = row0 + nl;
        if (gr < n) {
            float s = b[col];
#pragma unroll
            for (int k = 0; k < AGGD; k++)
                s = fmaf(rows[nl][k], sW[k * OUTD + col], s);
            A[(size_t)gr * OUTD + col] =
                PRESCALE ? fmaxf(s, 0.f) * dis[gr] : s;
        }
    }
}

// ---- graph bounds via binary search on sorted batch ------------------------
__global__ __launch_bounds__(256) void k_bounds(const int* __restrict__ batch,
                                                int* __restrict__ bounds,
                                                int n, int ngr) {
    int g = blockIdx.x * 256 + threadIdx.x;
    if (g > ngr) return;
    if (g == ngr) { bounds[g] = n; return; }
    int lo = 0, hi = n;
    while (lo < hi) {
        int mid = (lo + hi) >> 1;
        if (batch[mid] < g) lo = mid + 1; else hi = mid;
    }
    bounds[g] = lo;
}

// ---- per-graph mean of relu(A3), no atomics --------------------------------
__global__ __launch_bounds__(64) void k_pool(const float* __restrict__ A3,
                                             const int* __restrict__ bounds,
                                             float* __restrict__ pooled) {
    const int g = blockIdx.x, j = threadIdx.x;
    const int s = bounds[g], e = bounds[g + 1];
    float sum = 0.f;
    for (int node = s; node < e; node++)
        sum += fmaxf(A3[(size_t)node * 64 + j], 0.f);
    pooled[g * 64 + j] = sum / fmaxf((float)(e - s), 1.f);
}

// ---- head: fc1+relu -> fc2 -> softmax --------------------------------------
__global__ __launch_bounds__(64) void k_head(
        const float* __restrict__ pooled,
        const float* __restrict__ f1w, const float* __restrict__ f1b,
        const float* __restrict__ f2w, const float* __restrict__ f2b,
        float* __restrict__ out) {
    int g = blockIdx.x;
    int t = threadIdx.x;
    __shared__ float p[64], z[32], lg[16];
    p[t] = pooled[g * 64 + t];
    __syncthreads();
    if (t < 32) {
        float acc = f1b[t];
        for (int j = 0; j < 64; j++) acc = fmaf(p[j], f1w[j * 32 + t], acc);
        z[t] = fmaxf(acc, 0.f);
    }
    __syncthreads();
    if (t < 16) {
        float acc = f2b[t];
        for (int k = 0; k < 32; k++) acc = fmaf(z[k], f2w[k * 16 + t], acc);
        lg[t] = acc;
    }
    __syncthreads();
    if (t < 16) {
        float m = lg[0];
        for (int i = 1; i < 16; i++) m = fmaxf(m, lg[i]);
        float s = 0.f;
        for (int i = 0; i < 16; i++) s += expf(lg[i] - m);
        out[g * 16 + t] = expf(lg[t] - m) / s;
    }
}

extern "C" void kernel_launch(void* const* d_in, const int* in_sizes, int n_in,
                              void* d_out, int out_size, void* d_ws, size_t ws_size,
                              hipStream_t stream) {
    (void)in_sizes; (void)n_in; (void)out_size; (void)ws_size;
    const float* x     = (const float*)d_in[0];
    const int*   ei    = (const int*)d_in[1];
    const int*   batch = (const int*)d_in[2];
    const float* W1 = (const float*)d_in[3];  const float* b1 = (const float*)d_in[4];
    const float* W2 = (const float*)d_in[5];  const float* b2 = (const float*)d_in[6];
    const float* W3 = (const float*)d_in[7];  const float* b3 = (const float*)d_in[8];
    const float* f1w = (const float*)d_in[9]; const float* f1b = (const float*)d_in[10];
    const float* f2w = (const float*)d_in[11];const float* f2b = (const float*)d_in[12];
    float* out = (float*)d_out;

    const int* src = ei;
    const int* dst = ei + NE;

    // Workspace (~59.3 MB), lifetime-aliased arena of NN x 112 floats:
    //   H1'  = cols [0,32)    [gemm1 .. pull1]
    //   H2'  = cols [32,64)   [pull1 .. pull_mm2]   (relu(A1)*dis, fused)
    //   H3'  = cols [64,112)  [pull_mm2 .. pull_mm3]
    //   A3   = cols [0,64)    [pull_mm3 .. pool]    (H1',H2' dead by then)
    float* ws = (float*)d_ws;
    size_t o = 0;
    float* dis    = ws + o; o += NN;
    int*   degi   = (int*)(ws + o); o += NN;
    int*   offs   = (int*)(ws + o); o += NN;
    int*   cursor = (int*)(ws + o); o += NN;
    int*   csr    = (int*)(ws + o); o += NE;
    int*   bsum   = (int*)(ws + o); o += 128;
    int*   bscan  = (int*)(ws + o); o += 128;
    int*   bounds = (int*)(ws + o); o += NG + 8;
    float* pooled = ws + o; o += (size_t)NG * 64;
    float* R      = ws + o; o += (size_t)NN * 112;

    float* H1 = R;
    float* H2 = R + (size_t)NN * 32;
    float* H3 = R + (size_t)NN * 64;
    float* A3 = R;

    hipMemsetAsync(degi, 0, NN * sizeof(int), stream);

    // CSR build
    k_degree<<<(NE + 255) / 256, 256, 0, stream>>>(dst, degi, NE);
    k_dis<<<(NN + 255) / 256, 256, 0, stream>>>(degi, dis, NN);
    constexpr int NB1 = (NN + 1023) / 1024;  // 98
    k_scan1<<<NB1, 256, 0, stream>>>(degi, offs, bsum, NN);
    k_scan2<<<1, 128, 0, stream>>>(bsum, bscan, NB1);
    k_scan3<<<(NN + 255) / 256, 256, 0, stream>>>(offs, cursor, bscan, NN);
    k_fill<<<(NE + 255) / 256, 256, 0, stream>>>(src, dst, cursor, csr, NE);

    // Layer 1: transform-first (128->32), then pull; epilogue emits H2'
    k_gemm1<<<(NN + 7) / 8, 256, 0, stream>>>(x, W1, dis, H1, NN);
    k_pull<32, 16, true><<<(NN + 15) / 16, 256, 0, stream>>>(
        H1, offs, degi, csr, dis, b1, H2, NN);

    // Layer 2: pull(32) + fused gemm 32->48; epilogue emits H3'
    k_pull_mm<32, 48, 16, true><<<(NN + 15) / 16, 256, 0, stream>>>(
        H2, offs, degi, csr, dis, W2, b2, H3, NN);

    // Layer 3: pull(48) + fused gemm 48->64 -> A3
    k_pull_mm<48, 64, 16, false><<<(NN + 15) / 16, 256, 0, stream>>>(
        H3, offs, degi, csr, dis, W3, b3, A3, NN);

    // Pool (sorted batch -> bounds, no atomics) + head
    k_bounds<<<(NG + 1 + 255) / 256, 256, 0, stream>>>(batch, bounds, NN, NG);
    k_pool<<<NG, 64, 0, stream>>>(A3, bounds, pooled);
    k_head<<<NG, 64, 0, stream>>>(pooled, f1w, f1b, f2w, f2b, out);
}

// Round 4
// 966.930 us; speedup vs baseline: 1.8214x; 1.0113x over previous
//
#include <hip/hip_runtime.h>
#include <hip/hip_fp16.h>

static constexpr int NN = 100000;
static constexpr int NE = 3200000;
static constexpr int NG = 512;
static constexpr int NBUCK = (NN + 63) / 64;  // 1563 buckets of 64 dst nodes

// ---- coarse histogram of dst>>6 (LDS-staged) -------------------------------
__global__ __launch_bounds__(256) void k_bhist(const int* __restrict__ dst,
                                               int* __restrict__ bcount, int e) {
    __shared__ int h[NBUCK];
    for (int i = threadIdx.x; i < NBUCK; i += 256) h[i] = 0;
    __syncthreads();
    const int stride = gridDim.x * 256;
    for (int i = blockIdx.x * 256 + threadIdx.x; i < e; i += stride)
        atomicAdd(&h[dst[i] >> 6], 1);
    __syncthreads();
    for (int i = threadIdx.x; i < NBUCK; i += 256)
        if (h[i]) atomicAdd(&bcount[i], h[i]);
}

// ---- exclusive scan of bcount (single block) -> boffs, bcur ----------------
__global__ __launch_bounds__(256) void k_bscan(const int* __restrict__ bcount,
                                               int* __restrict__ boffs,
                                               int* __restrict__ bcur) {
    constexpr int CH = (NBUCK + 255) / 256;  // 7
    __shared__ int s[256];
    const int tid = threadIdx.x;
    int v[CH], t = 0;
#pragma unroll
    for (int c = 0; c < CH; c++) {
        int i = tid * CH + c;
        v[c] = (i < NBUCK) ? bcount[i] : 0;
        t += v[c];
    }
    s[tid] = t;
    __syncthreads();
    for (int off = 1; off < 256; off <<= 1) {
        int x = (tid >= off) ? s[tid - off] : 0;
        __syncthreads();
        s[tid] += x;
        __syncthreads();
    }
    int run = s[tid] - t;
#pragma unroll
    for (int c = 0; c < CH; c++) {
        int i = tid * CH + c;
        if (i < NBUCK) { boffs[i] = run; bcur[i] = run; }
        run += v[c];
    }
    if (tid == 255) boffs[NBUCK] = run;
}

// ---- bucket scatter: tmp[p] = (dst&63)<<17 | src  (17 bits: NN<2^17) -------
__global__ __launch_bounds__(256) void k_bucket(const int* __restrict__ src,
                                                const int* __restrict__ dst,
                                                int* __restrict__ bcur,
                                                unsigned* __restrict__ tmp, int e) {
    int i = blockIdx.x * 256 + threadIdx.x;
    if (i < e) {
        int d = dst[i];
        int p = atomicAdd(&bcur[d >> 6], 1);
        tmp[p] = ((unsigned)(d & 63) << 17) | (unsigned)src[i];
    }
}

// ---- per-bucket: sub-histogram + scan in LDS; emit degi/offs/dis + csr -----
__global__ __launch_bounds__(256) void k_fillb(const unsigned* __restrict__ tmp,
                                               const int* __restrict__ boffs,
                                               int* __restrict__ csr,
                                               int* __restrict__ degi,
                                               int* __restrict__ offs,
                                               float* __restrict__ dis, int n) {
    __shared__ int cnt[64];
    __shared__ int cur[64];
    const int b = blockIdx.x, tid = threadIdx.x;
    const int nb = b * 64;
    const int nmax = min(64, n - nb);
    if (tid < 64) cnt[tid] = 0;
    const int e0 = boffs[b], e1 = boffs[b + 1];
    __syncthreads();
    for (int e = e0 + tid; e < e1; e += 256)
        atomicAdd(&cnt[tmp[e] >> 17], 1);
    __syncthreads();
    if (tid == 0) {
        int run = e0;
        for (int j = 0; j < nmax; j++) { cur[j] = run; run += cnt[j]; }
    }
    __syncthreads();
    if (tid < nmax) {
        int node = nb + tid;
        int c = cnt[tid];
        degi[node] = c;
        offs[node] = cur[tid];
        dis[node] = rsqrtf((float)c + 1.0f);
    }
    for (int e = e0 + tid; e < e1; e += 256) {
        unsigned pk = tmp[e];
        int p = atomicAdd(&cur[pk >> 17], 1);
        csr[p] = (int)(pk & 0x1FFFFu);
    }
}

// ---- gemm1: H1' = half((x @ W1) * dis[row])  (128 -> 32) -------------------
__global__ __launch_bounds__(256) void k_gemm1(const float* __restrict__ X,
                                               const float* __restrict__ W,
                                               const float* __restrict__ dis,
                                               __half* __restrict__ H, int n) {
    constexpr int IN = 128, OUTD = 32, ROWS = 8;
    __shared__ float sW[IN * OUTD];
    __shared__ float sX[ROWS * IN];
    const int tid = threadIdx.x;
    for (int i = tid; i < IN * OUTD; i += 256) sW[i] = W[i];
    const int row0 = blockIdx.x * ROWS;
    for (int i = tid; i < ROWS * IN; i += 256) {
        int r = row0 + i / IN;
        sX[i] = (r < n) ? X[(size_t)r * IN + i % IN] : 0.f;
    }
    __syncthreads();
    const int lr = tid / OUTD;
    const int col = tid % OUTD;
    const int gr = row0 + lr;
    float acc = 0.f;
#pragma unroll 8
    for (int k = 0; k < IN; k++)
        acc = fmaf(sX[lr * IN + k], sW[k * OUTD + col], acc);
    if (gr < n) H[(size_t)gr * OUTD + col] = __float2half(acc * dis[gr]);
}

// ---- pull (layer1): raw = dis[d]*(H'[d]+sum H'[src]) + b -------------------
// PRESCALE: out = half(relu(raw)*dis[d])   else out = half(raw)
template <int AGGD, int TPN, bool PRESCALE>
__global__ __launch_bounds__(256) void k_pull(
        const __half* __restrict__ Hp, const int* __restrict__ offs,
        const int* __restrict__ degi, const int* __restrict__ csr,
        const float* __restrict__ dis, const float* __restrict__ b,
        __half* __restrict__ A, int n) {
    constexpr int CPT = AGGD / TPN;
    constexpr int NPB = 256 / TPN;
    const int group = threadIdx.x / TPN, j0 = threadIdx.x % TPN;
    const int d = blockIdx.x * NPB + group;
    if (d >= n) return;
    const size_t selfbase = (size_t)d * AGGD + j0;
    float acc[CPT];
#pragma unroll
    for (int c = 0; c < CPT; c++) acc[c] = __half2float(Hp[selfbase + c * TPN]);
    int e = offs[d];
    const int end = e + degi[d];
    for (; e + 3 < end; e += 4) {
        int s0 = csr[e], s1 = csr[e + 1], s2 = csr[e + 2], s3 = csr[e + 3];
        size_t b0 = (size_t)s0 * AGGD + j0, b1 = (size_t)s1 * AGGD + j0;
        size_t b2 = (size_t)s2 * AGGD + j0, b3 = (size_t)s3 * AGGD + j0;
#pragma unroll
        for (int c = 0; c < CPT; c++)
            acc[c] += (__half2float(Hp[b0 + c * TPN]) + __half2float(Hp[b1 + c * TPN])) +
                      (__half2float(Hp[b2 + c * TPN]) + __half2float(Hp[b3 + c * TPN]));
    }
    for (; e < end; e++) {
        size_t bb = (size_t)csr[e] * AGGD + j0;
#pragma unroll
        for (int c = 0; c < CPT; c++) acc[c] += __half2float(Hp[bb + c * TPN]);
    }
    const float dd = dis[d];
#pragma unroll
    for (int c = 0; c < CPT; c++) {
        float raw = fmaf(acc[c], dd, b[j0 + c * TPN]);
        A[selfbase + c * TPN] = __float2half(PRESCALE ? fmaxf(raw, 0.f) * dd : raw);
    }
}

// ---- fused pull + gemm (layers 2,3) ----------------------------------------
template <int AGGD, int OUTD, int TPN, bool PRESCALE>
__global__ __launch_bounds__(256) void k_pull_mm(
        const __half* __restrict__ Hp, const int* __restrict__ offs,
        const int* __restrict__ degi, const int* __restrict__ csr,
        const float* __restrict__ dis, const float* __restrict__ W,
        const float* __restrict__ b, __half* __restrict__ A, int n) {
    constexpr int CPT = AGGD / TPN;
    constexpr int NPB = 256 / TPN;
    constexpr int OPT = (NPB * OUTD) / 256;
    __shared__ float sW[AGGD * OUTD];
    __shared__ float rows[NPB][AGGD];
    for (int i = threadIdx.x; i < AGGD * OUTD; i += 256) sW[i] = W[i];
    const int group = threadIdx.x / TPN, j0 = threadIdx.x % TPN;
    const int d = blockIdx.x * NPB + group;
    if (d < n) {
        const size_t selfbase = (size_t)d * AGGD + j0;
        float acc[CPT];
#pragma unroll
        for (int c = 0; c < CPT; c++) acc[c] = __half2float(Hp[selfbase + c * TPN]);
        int e = offs[d];
        const int end = e + degi[d];
        for (; e + 3 < end; e += 4) {
            int s0 = csr[e], s1 = csr[e + 1], s2 = csr[e + 2], s3 = csr[e + 3];
            size_t b0 = (size_t)s0 * AGGD + j0, b1 = (size_t)s1 * AGGD + j0;
            size_t b2 = (size_t)s2 * AGGD + j0, b3 = (size_t)s3 * AGGD + j0;
#pragma unroll
            for (int c = 0; c < CPT; c++)
                acc[c] += (__half2float(Hp[b0 + c * TPN]) + __half2float(Hp[b1 + c * TPN])) +
                          (__half2float(Hp[b2 + c * TPN]) + __half2float(Hp[b3 + c * TPN]));
        }
        for (; e < end; e++) {
            size_t bb = (size_t)csr[e] * AGGD + j0;
#pragma unroll
            for (int c = 0; c < CPT; c++) acc[c] += __half2float(Hp[bb + c * TPN]);
        }
        const float dd = dis[d];
#pragma unroll
        for (int c = 0; c < CPT; c++) rows[group][j0 + c * TPN] = acc[c] * dd;
    }
    __syncthreads();
    const int row0 = blockIdx.x * NPB;
#pragma unroll
    for (int o = 0; o < OPT; o++) {
        int idx = o * 256 + threadIdx.x;
        int nl = idx / OUTD, col = idx % OUTD;
        int gr = row0 + nl;
        if (gr < n) {
            float s = b[col];
#pragma unroll
            for (int k = 0; k < AGGD; k++)
                s = fmaf(rows[nl][k], sW[k * OUTD + col], s);
            A[(size_t)gr * OUTD + col] =
                __float2half(PRESCALE ? fmaxf(s, 0.f) * dis[gr] : s);
        }
    }
}

// ---- graph bounds via binary search on sorted batch ------------------------
__global__ __launch_bounds__(256) void k_bounds(const int* __restrict__ batch,
                                                int* __restrict__ bounds,
                                                int n, int ngr) {
    int g = blockIdx.x * 256 + threadIdx.x;
    if (g > ngr) return;
    if (g == ngr) { bounds[g] = n; return; }
    int lo = 0, hi = n;
    while (lo < hi) {
        int mid = (lo + hi) >> 1;
        if (batch[mid] < g) lo = mid + 1; else hi = mid;
    }
    bounds[g] = lo;
}

// ---- per-graph mean of relu(A3) --------------------------------------------
__global__ __launch_bounds__(64) void k_pool(const __half* __restrict__ A3,
                                             const int* __restrict__ bounds,
                                             float* __restrict__ pooled) {
    const int g = blockIdx.x, j = threadIdx.x;
    const int s = bounds[g], e = bounds[g + 1];
    float sum = 0.f;
    for (int node = s; node < e; node++)
        sum += fmaxf(__half2float(A3[(size_t)node * 64 + j]), 0.f);
    pooled[g * 64 + j] = sum / fmaxf((float)(e - s), 1.f);
}

// ---- head: fc1+relu -> fc2 -> softmax --------------------------------------
__global__ __launch_bounds__(64) void k_head(
        const float* __restrict__ pooled,
        const float* __restrict__ f1w, const float* __restrict__ f1b,
        const float* __restrict__ f2w, const float* __restrict__ f2b,
        float* __restrict__ out) {
    int g = blockIdx.x;
    int t = threadIdx.x;
    __shared__ float p[64], z[32], lg[16];
    p[t] = pooled[g * 64 + t];
    __syncthreads();
    if (t < 32) {
        float acc = f1b[t];
        for (int j = 0; j < 64; j++) acc = fmaf(p[j], f1w[j * 32 + t], acc);
        z[t] = fmaxf(acc, 0.f);
    }
    __syncthreads();
    if (t < 16) {
        float acc = f2b[t];
        for (int k = 0; k < 32; k++) acc = fmaf(z[k], f2w[k * 16 + t], acc);
        lg[t] = acc;
    }
    __syncthreads();
    if (t < 16) {
        float m = lg[0];
        for (int i = 1; i < 16; i++) m = fmaxf(m, lg[i]);
        float s = 0.f;
        for (int i = 0; i < 16; i++) s += expf(lg[i] - m);
        out[g * 16 + t] = expf(lg[t] - m) / s;
    }
}

extern "C" void kernel_launch(void* const* d_in, const int* in_sizes, int n_in,
                              void* d_out, int out_size, void* d_ws, size_t ws_size,
                              hipStream_t stream) {
    (void)in_sizes; (void)n_in; (void)out_size; (void)ws_size;
    const float* x     = (const float*)d_in[0];
    const int*   ei    = (const int*)d_in[1];
    const int*   batch = (const int*)d_in[2];
    const float* W1 = (const float*)d_in[3];
    const float* b1 = (const float*)d_in[4];
    const float* W2 = (const float*)d_in[5];  const float* b2 = (const float*)d_in[6];
    const float* W3 = (const float*)d_in[7];  const float* b3 = (const float*)d_in[8];
    const float* f1w = (const float*)d_in[9]; const float* f1b = (const float*)d_in[10];
    const float* f2w = (const float*)d_in[11];const float* f2b = (const float*)d_in[12];
    float* out = (float*)d_out;

    const int* src = ei;
    const int* dst = ei + NE;

    // Workspace (~37 MB). Region T (NN*112 halves = 22.4MB) is lifetime-aliased:
    //   tmp (uint, NE*4B=12.8MB)      [k_bucket .. k_fillb]
    //   H1' half cols[0,32)           [gemm1 .. pull1]
    //   H2' half cols[32,64)          [pull1 .. pull_mm2]
    //   H3' half cols[64,112)         [pull_mm2 .. pull_mm3]
    //   A3  half cols[0,64)           [pull_mm3 .. pool]   (H1,H2 dead)
    float* ws = (float*)d_ws;
    size_t o = 0;
    float* dis    = ws + o; o += NN;
    int*   degi   = (int*)(ws + o); o += NN;
    int*   offs   = (int*)(ws + o); o += NN;
    int*   bcount = (int*)(ws + o); o += NBUCK;
    int*   boffs  = (int*)(ws + o); o += NBUCK + 1;
    int*   bcur   = (int*)(ws + o); o += NBUCK;
    int*   bounds = (int*)(ws + o); o += NG + 1;
    float* pooled = ws + o; o += (size_t)NG * 64;
    int*   csr    = (int*)(ws + o); o += NE;
    __half* T     = (__half*)(ws + o); o += (size_t)NN * 56;  // NN*112 halves

    unsigned* tmp = (unsigned*)T;
    __half* H1 = T;
    __half* H2 = T + (size_t)NN * 32;
    __half* H3 = T + (size_t)NN * 64;
    __half* A3 = T;

    hipMemsetAsync(bcount, 0, NBUCK * sizeof(int), stream);

    // CSR build: coarse-bucket counting sort (no 100k-way random atomics)
    k_bhist<<<256, 256, 0, stream>>>(dst, bcount, NE);
    k_bscan<<<1, 256, 0, stream>>>(bcount, boffs, bcur);
    k_bucket<<<(NE + 255) / 256, 256, 0, stream>>>(src, dst, bcur, tmp, NE);
    k_fillb<<<NBUCK, 256, 0, stream>>>(tmp, boffs, csr, degi, offs, dis, NN);

    // Layer 1: transform-first (128->32), then pull; epilogue emits H2'
    k_gemm1<<<(NN + 7) / 8, 256, 0, stream>>>(x, W1, dis, H1, NN);
    k_pull<32, 16, true><<<(NN + 15) / 16, 256, 0, stream>>>(
        H1, offs, degi, csr, dis, b1, H2, NN);

    // Layer 2: pull(32) + fused gemm 32->48; epilogue emits H3'
    k_pull_mm<32, 48, 16, true><<<(NN + 15) / 16, 256, 0, stream>>>(
        H2, offs, degi, csr, dis, W2, b2, H3, NN);

    // Layer 3: pull(48) + fused gemm 48->64 -> A3
    k_pull_mm<48, 64, 16, false><<<(NN + 15) / 16, 256, 0, stream>>>(
        H3, offs, degi, csr, dis, W3, b3, A3, NN);

    // Pool (sorted batch -> bounds, no atomics) + head
    k_bounds<<<(NG + 1 + 255) / 256, 256, 0, stream>>>(batch, bounds, NN, NG);
    k_pool<<<NG, 64, 0, stream>>>(A3, bounds, pooled);
    k_head<<<NG, 64, 0, stream>>>(pooled, f1w, f1b, f2w, f2b, out);
}

// Round 5
// 552.395 us; speedup vs baseline: 3.1883x; 1.7504x over previous
//
#include <hip/hip_runtime.h>
#include <hip/hip_fp16.h>

static constexpr int NN = 100000;
static constexpr int NE = 3200000;
static constexpr int NG = 512;
static constexpr int NBUCK = (NN + 63) / 64;              // 1563 buckets x 64 nodes
static constexpr int CHUNK = 16384;
static constexpr int NCHUNK = (NE + CHUNK - 1) / CHUNK;   // 196 chunks
static constexpr int NCNT = NBUCK * NCHUNK;               // 306348 count cells
static constexpr int SCAN_BLK = 2048;                     // elems per scan block
static constexpr int NSB = (NCNT + SCAN_BLK - 1) / SCAN_BLK; // 150

// ---- per-chunk bucket histogram: cnts[bucket*NCHUNK + chunk] ---------------
__global__ __launch_bounds__(256) void k_chunkhist(const int* __restrict__ dst,
                                                   int* __restrict__ cnts, int e) {
    __shared__ int h[NBUCK];
    for (int i = threadIdx.x; i < NBUCK; i += 256) h[i] = 0;
    __syncthreads();
    const int s = blockIdx.x * CHUNK, eend = min(s + CHUNK, e);
    for (int i = s + threadIdx.x; i < eend; i += 256)
        atomicAdd(&h[dst[i] >> 6], 1);
    __syncthreads();
    for (int i = threadIdx.x; i < NBUCK; i += 256)
        cnts[(size_t)i * NCHUNK + blockIdx.x] = h[i];
}

// ---- generic 3-kernel exclusive scan (2048 elems / block) ------------------
__global__ __launch_bounds__(256) void k_scanA(const int* __restrict__ in,
                                               int* __restrict__ out,
                                               int* __restrict__ bsum, int n) {
    __shared__ int s[256];
    const int tid = threadIdx.x;
    const int base = blockIdx.x * SCAN_BLK + tid * 8;
    int v[8], t = 0;
#pragma unroll
    for (int c = 0; c < 8; c++) {
        int idx = base + c;
        v[c] = (idx < n) ? in[idx] : 0;
        t += v[c];
    }
    s[tid] = t;
    __syncthreads();
    for (int off = 1; off < 256; off <<= 1) {
        int x = (tid >= off) ? s[tid - off] : 0;
        __syncthreads();
        s[tid] += x;
        __syncthreads();
    }
    if (tid == 255) bsum[blockIdx.x] = s[255];
    int run = s[tid] - t;
#pragma unroll
    for (int c = 0; c < 8; c++) {
        int idx = base + c;
        if (idx < n) out[idx] = run;
        run += v[c];
    }
}

__global__ __launch_bounds__(256) void k_scanB(int* __restrict__ bsum, int nb) {
    __shared__ int s[256];
    const int tid = threadIdx.x;
    int v = (tid < nb) ? bsum[tid] : 0;
    s[tid] = v;
    __syncthreads();
    for (int off = 1; off < 256; off <<= 1) {
        int x = (tid >= off) ? s[tid - off] : 0;
        __syncthreads();
        s[tid] += x;
        __syncthreads();
    }
    if (tid < nb) bsum[tid] = s[tid] - v;  // exclusive, in place
}

__global__ __launch_bounds__(256) void k_scanC(int* __restrict__ out,
                                               const int* __restrict__ bsum, int n) {
    int i = blockIdx.x * 256 + threadIdx.x;
    if (i < n) out[i] += bsum[i / SCAN_BLK];
}

// ---- place: tmp[pos] = (dst&63)<<17 | src, pos from scanned cnts (no atomics)
__global__ __launch_bounds__(256) void k_place(const int* __restrict__ src,
                                               const int* __restrict__ dst,
                                               const int* __restrict__ sc,
                                               unsigned* __restrict__ tmp, int e) {
    __shared__ int cur[NBUCK];
    for (int i = threadIdx.x; i < NBUCK; i += 256)
        cur[i] = sc[(size_t)i * NCHUNK + blockIdx.x];
    __syncthreads();
    const int s = blockIdx.x * CHUNK, eend = min(s + CHUNK, e);
    for (int i = s + threadIdx.x; i < eend; i += 256) {
        int d = dst[i];
        int p = atomicAdd(&cur[d >> 6], 1);
        tmp[p] = ((unsigned)(d & 63) << 17) | (unsigned)src[i];
    }
}

// ---- per-bucket: sub-histogram + scan in LDS; emit degi/offs/dis + csr -----
__global__ __launch_bounds__(256) void k_fillb(const unsigned* __restrict__ tmp,
                                               const int* __restrict__ sc,
                                               int* __restrict__ csr,
                                               int* __restrict__ degi,
                                               int* __restrict__ offs,
                                               float* __restrict__ dis,
                                               int n, int etotal) {
    __shared__ int cnt[64];
    __shared__ int cur[64];
    const int b = blockIdx.x, tid = threadIdx.x;
    const int nb = b * 64;
    const int nmax = min(64, n - nb);
    if (tid < 64) cnt[tid] = 0;
    const int e0 = sc[(size_t)b * NCHUNK];
    const int e1 = (b + 1 < NBUCK) ? sc[(size_t)(b + 1) * NCHUNK] : etotal;
    __syncthreads();
    for (int e = e0 + tid; e < e1; e += 256)
        atomicAdd(&cnt[tmp[e] >> 17], 1);
    __syncthreads();
    if (tid == 0) {
        int run = e0;
        for (int j = 0; j < nmax; j++) { cur[j] = run; run += cnt[j]; }
    }
    __syncthreads();
    if (tid < nmax) {
        int node = nb + tid;
        int c = cnt[tid];
        degi[node] = c;
        offs[node] = cur[tid];
        dis[node] = rsqrtf((float)c + 1.0f);
    }
    for (int e = e0 + tid; e < e1; e += 256) {
        unsigned pk = tmp[e];
        int p = atomicAdd(&cur[pk >> 17], 1);
        csr[p] = (int)(pk & 0x1FFFFu);
    }
}

// ---- gemm1: H1' = half((x @ W1) * dis[row])  (128 -> 32) -------------------
__global__ __launch_bounds__(256) void k_gemm1(const float* __restrict__ X,
                                               const float* __restrict__ W,
                                               const float* __restrict__ dis,
                                               __half* __restrict__ H, int n) {
    constexpr int IN = 128, OUTD = 32, ROWS = 8;
    __shared__ float sW[IN * OUTD];
    __shared__ float sX[ROWS * IN];
    const int tid = threadIdx.x;
    for (int i = tid; i < IN * OUTD; i += 256) sW[i] = W[i];
    const int row0 = blockIdx.x * ROWS;
    for (int i = tid; i < ROWS * IN; i += 256) {
        int r = row0 + i / IN;
        sX[i] = (r < n) ? X[(size_t)r * IN + i % IN] : 0.f;
    }
    __syncthreads();
    const int lr = tid / OUTD;
    const int col = tid % OUTD;
    const int gr = row0 + lr;
    float acc = 0.f;
#pragma unroll 8
    for (int k = 0; k < IN; k++)
        acc = fmaf(sX[lr * IN + k], sW[k * OUTD + col], acc);
    if (gr < n) H[(size_t)gr * OUTD + col] = __float2half(acc * dis[gr]);
}

// ---- layer-1 pull, 32-dim, __half2 gathers ---------------------------------
// out = half2( relu(dis*(self+sum)+b) * dis )
__global__ __launch_bounds__(256) void k_pull2(
        const __half2* __restrict__ Hp, const int* __restrict__ offs,
        const int* __restrict__ degi, const int* __restrict__ csr,
        const float* __restrict__ dis, const float* __restrict__ b,
        __half2* __restrict__ A, int n) {
    const int group = threadIdx.x >> 4, j0 = threadIdx.x & 15;
    const int d = blockIdx.x * 16 + group;
    if (d >= n) return;
    const size_t self = (size_t)d * 16 + j0;
    __half2 hv = Hp[self];
    float a0 = __low2float(hv), a1 = __high2float(hv);
    int e = offs[d];
    const int end = e + degi[d];
    for (; e + 3 < end; e += 4) {
        int s0 = csr[e], s1 = csr[e + 1], s2 = csr[e + 2], s3 = csr[e + 3];
        __half2 v0 = Hp[(size_t)s0 * 16 + j0], v1 = Hp[(size_t)s1 * 16 + j0];
        __half2 v2 = Hp[(size_t)s2 * 16 + j0], v3 = Hp[(size_t)s3 * 16 + j0];
        a0 += (__low2float(v0) + __low2float(v1)) + (__low2float(v2) + __low2float(v3));
        a1 += (__high2float(v0) + __high2float(v1)) + (__high2float(v2) + __high2float(v3));
    }
    for (; e < end; e++) {
        __half2 v = Hp[(size_t)csr[e] * 16 + j0];
        a0 += __low2float(v); a1 += __high2float(v);
    }
    const float dd = dis[d];
    float r0 = fmaf(a0, dd, b[2 * j0]);
    float r1 = fmaf(a1, dd, b[2 * j0 + 1]);
    r0 = fmaxf(r0, 0.f) * dd;
    r1 = fmaxf(r1, 0.f) * dd;
    A[self] = __floats2half2_rn(r0, r1);
}

// ---- layer-2: pull 32-dim (__half2) + fused gemm 32->48, prescaled out -----
__global__ __launch_bounds__(256) void k_pullmm32(
        const __half2* __restrict__ Hp, const int* __restrict__ offs,
        const int* __restrict__ degi, const int* __restrict__ csr,
        const float* __restrict__ dis, const float* __restrict__ W,
        const float* __restrict__ b, __half* __restrict__ A, int n) {
    __shared__ float sW[32 * 48];
    __shared__ float rows[16][32];
    for (int i = threadIdx.x; i < 32 * 48; i += 256) sW[i] = W[i];
    const int group = threadIdx.x >> 4, j0 = threadIdx.x & 15;
    const int d = blockIdx.x * 16 + group;
    if (d < n) {
        const size_t self = (size_t)d * 16 + j0;
        __half2 hv = Hp[self];
        float a0 = __low2float(hv), a1 = __high2float(hv);
        int e = offs[d];
        const int end = e + degi[d];
        for (; e + 3 < end; e += 4) {
            int s0 = csr[e], s1 = csr[e + 1], s2 = csr[e + 2], s3 = csr[e + 3];
            __half2 v0 = Hp[(size_t)s0 * 16 + j0], v1 = Hp[(size_t)s1 * 16 + j0];
            __half2 v2 = Hp[(size_t)s2 * 16 + j0], v3 = Hp[(size_t)s3 * 16 + j0];
            a0 += (__low2float(v0) + __low2float(v1)) + (__low2float(v2) + __low2float(v3));
            a1 += (__high2float(v0) + __high2float(v1)) + (__high2float(v2) + __high2float(v3));
        }
        for (; e < end; e++) {
            __half2 v = Hp[(size_t)csr[e] * 16 + j0];
            a0 += __low2float(v); a1 += __high2float(v);
        }
        const float dd = dis[d];
        rows[group][2 * j0]     = a0 * dd;
        rows[group][2 * j0 + 1] = a1 * dd;
    }
    __syncthreads();
    const int row0 = blockIdx.x * 16;
#pragma unroll
    for (int o = 0; o < 3; o++) {
        int idx = o * 256 + threadIdx.x;
        int nl = idx / 48, col = idx % 48;
        int gr = row0 + nl;
        if (gr < n) {
            float s = b[col];
#pragma unroll
            for (int k = 0; k < 32; k++)
                s = fmaf(rows[nl][k], sW[k * 48 + col], s);
            A[(size_t)gr * 48 + col] = __float2half(fmaxf(s, 0.f) * dis[gr]);
        }
    }
}

// ---- layer-3: pull 48-dim (scalar) + fused gemm 48->64 ---------------------
__global__ __launch_bounds__(256) void k_pullmm48(
        const __half* __restrict__ Hp, const int* __restrict__ offs,
        const int* __restrict__ degi, const int* __restrict__ csr,
        const float* __restrict__ dis, const float* __restrict__ W,
        const float* __restrict__ b, __half* __restrict__ A, int n) {
    constexpr int AGGD = 48, OUTD = 64;
    __shared__ float sW[AGGD * OUTD];
    __shared__ float rows[16][AGGD];
    for (int i = threadIdx.x; i < AGGD * OUTD; i += 256) sW[i] = W[i];
    const int group = threadIdx.x >> 4, j0 = threadIdx.x & 15;
    const int d = blockIdx.x * 16 + group;
    if (d < n) {
        const size_t self = (size_t)d * AGGD + j0;
        float acc[3];
#pragma unroll
        for (int c = 0; c < 3; c++) acc[c] = __half2float(Hp[self + c * 16]);
        int e = offs[d];
        const int end = e + degi[d];
        for (; e + 3 < end; e += 4) {
            int s0 = csr[e], s1 = csr[e + 1], s2 = csr[e + 2], s3 = csr[e + 3];
            size_t b0 = (size_t)s0 * AGGD + j0, b1 = (size_t)s1 * AGGD + j0;
            size_t b2 = (size_t)s2 * AGGD + j0, b3 = (size_t)s3 * AGGD + j0;
#pragma unroll
            for (int c = 0; c < 3; c++)
                acc[c] += (__half2float(Hp[b0 + c * 16]) + __half2float(Hp[b1 + c * 16])) +
                          (__half2float(Hp[b2 + c * 16]) + __half2float(Hp[b3 + c * 16]));
        }
        for (; e < end; e++) {
            size_t bb = (size_t)csr[e] * AGGD + j0;
#pragma unroll
            for (int c = 0; c < 3; c++) acc[c] += __half2float(Hp[bb + c * 16]);
        }
        const float dd = dis[d];
#pragma unroll
        for (int c = 0; c < 3; c++) rows[group][j0 + c * 16] = acc[c] * dd;
    }
    __syncthreads();
    const int row0 = blockIdx.x * 16;
#pragma unroll
    for (int o = 0; o < 4; o++) {
        int idx = o * 256 + threadIdx.x;
        int nl = idx / OUTD, col = idx % OUTD;
        int gr = row0 + nl;
        if (gr < n) {
            float s = b[col];
#pragma unroll
            for (int k = 0; k < AGGD; k++)
                s = fmaf(rows[nl][k], sW[k * OUTD + col], s);
            A[(size_t)gr * OUTD + col] = __float2half(s);
        }
    }
}

// ---- graph bounds via binary search on sorted batch ------------------------
__global__ __launch_bounds__(256) void k_bounds(const int* __restrict__ batch,
                                                int* __restrict__ bounds,
                                                int n, int ngr) {
    int g = blockIdx.x * 256 + threadIdx.x;
    if (g > ngr) return;
    if (g == ngr) { bounds[g] = n; return; }
    int lo = 0, hi = n;
    while (lo < hi) {
        int mid = (lo + hi) >> 1;
        if (batch[mid] < g) lo = mid + 1; else hi = mid;
    }
    bounds[g] = lo;
}

// ---- per-graph mean of relu(A3) --------------------------------------------
__global__ __launch_bounds__(64) void k_pool(const __half* __restrict__ A3,
                                             const int* __restrict__ bounds,
                                             float* __restrict__ pooled) {
    const int g = blockIdx.x, j = threadIdx.x;
    const int s = bounds[g], e = bounds[g + 1];
    float sum = 0.f;
    for (int node = s; node < e; node++)
        sum += fmaxf(__half2float(A3[(size_t)node * 64 + j]), 0.f);
    pooled[g * 64 + j] = sum / fmaxf((float)(e - s), 1.f);
}

// ---- head: fc1+relu -> fc2 -> softmax --------------------------------------
__global__ __launch_bounds__(64) void k_head(
        const float* __restrict__ pooled,
        const float* __restrict__ f1w, const float* __restrict__ f1b,
        const float* __restrict__ f2w, const float* __restrict__ f2b,
        float* __restrict__ out) {
    int g = blockIdx.x;
    int t = threadIdx.x;
    __shared__ float p[64], z[32], lg[16];
    p[t] = pooled[g * 64 + t];
    __syncthreads();
    if (t < 32) {
        float acc = f1b[t];
        for (int j = 0; j < 64; j++) acc = fmaf(p[j], f1w[j * 32 + t], acc);
        z[t] = fmaxf(acc, 0.f);
    }
    __syncthreads();
    if (t < 16) {
        float acc = f2b[t];
        for (int k = 0; k < 32; k++) acc = fmaf(z[k], f2w[k * 16 + t], acc);
        lg[t] = acc;
    }
    __syncthreads();
    if (t < 16) {
        float m = lg[0];
        for (int i = 1; i < 16; i++) m = fmaxf(m, lg[i]);
        float s = 0.f;
        for (int i = 0; i < 16; i++) s += expf(lg[i] - m);
        out[g * 16 + t] = expf(lg[t] - m) / s;
    }
}

extern "C" void kernel_launch(void* const* d_in, const int* in_sizes, int n_in,
                              void* d_out, int out_size, void* d_ws, size_t ws_size,
                              hipStream_t stream) {
    (void)in_sizes; (void)n_in; (void)out_size; (void)ws_size;
    const float* x     = (const float*)d_in[0];
    const int*   ei    = (const int*)d_in[1];
    const int*   batch = (const int*)d_in[2];
    const float* W1 = (const float*)d_in[3];
    const float* b1 = (const float*)d_in[4];
    const float* W2 = (const float*)d_in[5];  const float* b2 = (const float*)d_in[6];
    const float* W3 = (const float*)d_in[7];  const float* b3 = (const float*)d_in[8];
    const float* f1w = (const float*)d_in[9]; const float* f1b = (const float*)d_in[10];
    const float* f2w = (const float*)d_in[11];const float* f2b = (const float*)d_in[12];
    float* out = (float*)d_out;

    const int* src = ei;
    const int* dst = ei + NE;

    // Workspace (~39 MB). Region T (NN*112 halves) lifetime-aliased:
    //   tmp uint[NE]          [k_place .. k_fillb]
    //   H1' half cols[0,32)   [gemm1 .. pull2]
    //   H2' half cols[32,64)  [pull2 .. pullmm32]
    //   H3' half cols[64,112) [pullmm32 .. pullmm48]
    //   A3  half cols[0,64)   [pullmm48 .. pool]
    float* ws = (float*)d_ws;
    size_t o = 0;
    float* dis    = ws + o; o += NN;
    int*   degi   = (int*)(ws + o); o += NN;
    int*   offs   = (int*)(ws + o); o += NN;
    int*   cnts   = (int*)(ws + o); o += NCNT;
    int*   sc     = (int*)(ws + o); o += NCNT;
    int*   bsum   = (int*)(ws + o); o += NSB + 8;
    int*   bounds = (int*)(ws + o); o += NG + 1;
    float* pooled = ws + o; o += (size_t)NG * 64;
    int*   csr    = (int*)(ws + o); o += NE;
    __half* T     = (__half*)(ws + o); o += (size_t)NN * 56;  // NN*112 halves

    unsigned* tmp = (unsigned*)T;
    __half* H1 = T;
    __half* H2 = T + (size_t)NN * 32;
    __half* H3 = T + (size_t)NN * 64;
    __half* A3 = T;

    // CSR build: chunked counting sort, zero contended global atomics
    k_chunkhist<<<NCHUNK, 256, 0, stream>>>(dst, cnts, NE);
    k_scanA<<<NSB, 256, 0, stream>>>(cnts, sc, bsum, NCNT);
    k_scanB<<<1, 256, 0, stream>>>(bsum, NSB);
    k_scanC<<<(NCNT + 255) / 256, 256, 0, stream>>>(sc, bsum, NCNT);
    k_place<<<NCHUNK, 256, 0, stream>>>(src, dst, sc, tmp, NE);
    k_fillb<<<NBUCK, 256, 0, stream>>>(tmp, sc, csr, degi, offs, dis, NN, NE);

    // Layer 1: transform-first (128->32), then pull (half2); emits H2'
    k_gemm1<<<(NN + 7) / 8, 256, 0, stream>>>(x, W1, dis, H1, NN);
    k_pull2<<<(NN + 15) / 16, 256, 0, stream>>>(
        (const __half2*)H1, offs, degi, csr, dis, b1, (__half2*)H2, NN);

    // Layer 2: pull(32, half2) + fused gemm 32->48; emits H3'
    k_pullmm32<<<(NN + 15) / 16, 256, 0, stream>>>(
        (const __half2*)H2, offs, degi, csr, dis, W2, b2, H3, NN);

    // Layer 3: pull(48) + fused gemm 48->64 -> A3
    k_pullmm48<<<(NN + 15) / 16, 256, 0, stream>>>(
        H3, offs, degi, csr, dis, W3, b3, A3, NN);

    // Pool (sorted batch -> bounds, no atomics) + head
    k_bounds<<<(NG + 1 + 255) / 256, 256, 0, stream>>>(batch, bounds, NN, NG);
    k_pool<<<NG, 64, 0, stream>>>(A3, bounds, pooled);
    k_head<<<NG, 64, 0, stream>>>(pooled, f1w, f1b, f2w, f2b, out);
}